// Round 1
// baseline (129.838 us; speedup 1.0000x reference)
//
#include <hip/hip_runtime.h>
#include <math.h>

#define EDIM 128
#define BB   256
#define SS   512
#define NWAVE 16
#define BLOCK (NWAVE * 64)

// DPP-based add: runs on VALU, keeps the DS pipe free.
template<int CTRL>
__device__ __forceinline__ float dpp_add(float v) {
    int r = __builtin_amdgcn_update_dpp(0, __float_as_int(v), CTRL, 0xF, 0xF, true);
    return v + __int_as_float(r);
}

// Sum across the 16 lanes of a DPP row (all 16 lanes get the total).
__device__ __forceinline__ float rowsum16(float v) {
    v = dpp_add<0xB1>(v);    // quad_perm [1,0,3,2]  (xor 1)
    v = dpp_add<0x4E>(v);    // quad_perm [2,3,0,1]  (xor 2)
    v = dpp_add<0x124>(v);   // row_ror:4
    v = dpp_add<0x128>(v);   // row_ror:8
    return v;
}

__global__ __launch_bounds__(BLOCK)
void fused_embed_attn_kernel(const int* __restrict__ x,
                             const float* __restrict__ emb,
                             const float* __restrict__ Wq,
                             const float* __restrict__ bq,
                             const float* __restrict__ Wm,
                             const float* __restrict__ bm,
                             float* __restrict__ out)
{
    const int b    = blockIdx.x;
    const int tid  = threadIdx.x;
    const int wave = tid >> 6;
    const int lane = tid & 63;
    const int row  = lane >> 4;   // 4 token-groups (DPP rows) per wave
    const int slot = lane & 15;   // 16 lanes per token
    // Contiguous-halves layout: lane owns dims [d0,d0+4) and [64+d0,64+d0+4).
    // Each gather instruction's 16 lanes now cover a CONTIGUOUS 256 B half-row
    // (one request per 64 B line) instead of stride-32 B half-density, which
    // doubled the L1/L2 line-request count for the same bytes.
    const int d0   = slot * 4;

    const float4 wq0 = *reinterpret_cast<const float4*>(Wq + d0);
    const float4 wq1 = *reinterpret_cast<const float4*>(Wq + 64 + d0);
    const float  bq0 = bq[0];

    // This lane's group owns 8 consecutive tokens (same indices across the
    // 16-lane row -> broadcast loads).
    const int tbase = b * SS + wave * 32 + row * 8;
    const int4 ia = *reinterpret_cast<const int4*>(x + tbase);
    const int4 ib = *reinterpret_cast<const int4*>(x + tbase + 4);
    const int idx[8] = {ia.x, ia.y, ia.z, ia.w, ib.x, ib.y, ib.z, ib.w};

    // ---- issue ALL gather loads up front: 16 outstanding float4s/lane ----
    float4 e0[8], e1[8];
    #pragma unroll
    for (int i = 0; i < 8; ++i) {
        const float* rp = emb + (size_t)idx[i] * EDIM;
        e0[i] = *reinterpret_cast<const float4*>(rp + d0);        // bytes 0..256 of row
        e1[i] = *reinterpret_cast<const float4*>(rp + 64 + d0);   // bytes 256..512
    }

    // ---- pass 1: logits for all 8 tokens (independent DPP chains, good ILP)
    float lp[8];
    #pragma unroll
    for (int i = 0; i < 8; ++i) {
        float q = e0[i].x * wq0.x + e0[i].y * wq0.y + e0[i].z * wq0.z + e0[i].w * wq0.w
                + e1[i].x * wq1.x + e1[i].y * wq1.y + e1[i].z * wq1.z + e1[i].w * wq1.w;
        float s = e0[i].x + e0[i].y + e0[i].z + e0[i].w
                + e1[i].x + e1[i].y + e1[i].z + e1[i].w;
        q = rowsum16(q);                   // VALU DPP, no DS traffic
        s = rowsum16(s);
        lp[i] = (q + bq0) * s;
    }

    // ---- pass 2: batch-max softmax over the 8 resident tokens.
    // All embeddings are live in registers, so no online rescale is needed:
    // one exp + 8 FMA per token instead of 2 exp + 16 ops + serial al-chain.
    const float m = fmaxf(fmaxf(fmaxf(lp[0], lp[1]), fmaxf(lp[2], lp[3])),
                          fmaxf(fmaxf(lp[4], lp[5]), fmaxf(lp[6], lp[7])));

    float Z = 0.f;
    float acc[8] = {0.f, 0.f, 0.f, 0.f, 0.f, 0.f, 0.f, 0.f};
    #pragma unroll
    for (int i = 0; i < 8; ++i) {
        const float w = __expf(lp[i] - m);   // uniform within the 16-lane row
        Z += w;
        acc[0] = fmaf(w, e0[i].x, acc[0]);  acc[1] = fmaf(w, e0[i].y, acc[1]);
        acc[2] = fmaf(w, e0[i].z, acc[2]);  acc[3] = fmaf(w, e0[i].w, acc[3]);
        acc[4] = fmaf(w, e1[i].x, acc[4]);  acc[5] = fmaf(w, e1[i].y, acc[5]);
        acc[6] = fmaf(w, e1[i].z, acc[6]);  acc[7] = fmaf(w, e1[i].w, acc[7]);
    }

    // ---- merge the wave's 4 row-groups (cross-row -> shuffles, once) ----
    float m1 = fmaxf(m, __shfl_xor(m, 16));
    const float M  = fmaxf(m1, __shfl_xor(m1, 32));
    const float sc = __expf(m - M);
    float Zs = Z * sc;
    Zs += __shfl_xor(Zs, 16);
    Zs += __shfl_xor(Zs, 32);
    #pragma unroll
    for (int j = 0; j < 8; ++j) {
        float a = acc[j] * sc;
        a += __shfl_xor(a, 16);
        a += __shfl_xor(a, 32);
        acc[j] = a;
    }

    // ---- block-level merge of the 16 wave partials ----
    __shared__ float sm[NWAVE];
    __shared__ float szv[NWAVE];
    __shared__ float sacc[NWAVE][EDIM];

    if (row == 0) {
        *reinterpret_cast<float4*>(&sacc[wave][d0])      = make_float4(acc[0], acc[1], acc[2], acc[3]);
        *reinterpret_cast<float4*>(&sacc[wave][64 + d0]) = make_float4(acc[4], acc[5], acc[6], acc[7]);
        if (slot == 0) { sm[wave] = M; szv[wave] = Zs; }
    }
    __syncthreads();

    // wave 0: combine partials, project [128]x[128,2], relu, store
    if (tid < 64) {
        float Mb = sm[0];
        #pragma unroll
        for (int w = 1; w < NWAVE; ++w) Mb = fmaxf(Mb, sm[w]);
        float zt = 0.f, tv0 = 0.f, tv1 = 0.f;
        #pragma unroll
        for (int w = 0; w < NWAVE; ++w) {
            const float s2 = __expf(sm[w] - Mb);
            zt += szv[w] * s2;
            const float2 a2 = *reinterpret_cast<const float2*>(&sacc[w][2 * tid]);
            tv0 = fmaf(a2.x, s2, tv0);
            tv1 = fmaf(a2.y, s2, tv1);
        }
        const float t0 = tv0 / zt, t1 = tv1 / zt;   // t_hat dims 2*tid, 2*tid+1
        const float4 wm = *reinterpret_cast<const float4*>(Wm + 4 * tid);
        float c0 = t0 * wm.x + t1 * wm.z;
        float c1 = t0 * wm.y + t1 * wm.w;
        #pragma unroll
        for (int off = 32; off >= 1; off >>= 1) {
            c0 += __shfl_xor(c0, off);
            c1 += __shfl_xor(c1, off);
        }
        if (tid == 0) {
            out[b * 2 + 0] = fmaxf(c0 + bm[0], 0.f);
            out[b * 2 + 1] = fmaxf(c1 + bm[1], 0.f);
        }
    }
}

extern "C" void kernel_launch(void* const* d_in, const int* in_sizes, int n_in,
                              void* d_out, int out_size, void* d_ws, size_t ws_size,
                              hipStream_t stream) {
    const int*   x   = (const int*)  d_in[0];
    const float* emb = (const float*)d_in[1];
    const float* Wq  = (const float*)d_in[2];
    const float* bq  = (const float*)d_in[3];
    const float* Wm  = (const float*)d_in[4];
    const float* bm  = (const float*)d_in[5];
    float* out = (float*)d_out;

    hipLaunchKernelGGL(fused_embed_attn_kernel, dim3(BB), dim3(BLOCK), 0,
                       stream, x, emb, Wq, bq, Wm, bm, out);
}

// Round 2
// 99.082 us; speedup vs baseline: 1.3104x; 1.3104x over previous
//
#include <hip/hip_runtime.h>
#include <math.h>

#define EDIM 128
#define BB   256
#define SS   512

// Partials layout in workspace: per (b, wave-chunk) record of 132 floats:
//   [0..127] acc (unnormalized weighted embedding sum, scaled to local max)
//   [128] M (local max logit)  [129] Z (local partition sum)  [130..131] pad
#define CHUNKS_PER_B 32          // 32 waves per batch row, 16 tokens each
#define REC 132

// DPP-based add: runs on VALU, keeps the DS pipe free.
template<int CTRL>
__device__ __forceinline__ float dpp_add(float v) {
    int r = __builtin_amdgcn_update_dpp(0, __float_as_int(v), CTRL, 0xF, 0xF, true);
    return v + __int_as_float(r);
}

// Sum across the 16 lanes of a DPP row (all 16 lanes get the total).
__device__ __forceinline__ float rowsum16(float v) {
    v = dpp_add<0xB1>(v);    // quad_perm [1,0,3,2]  (xor 1)
    v = dpp_add<0x4E>(v);    // quad_perm [2,3,0,1]  (xor 2)
    v = dpp_add<0x124>(v);   // row_ror:4
    v = dpp_add<0x128>(v);   // row_ror:8
    return v;
}

// ---------------------------------------------------------------------------
// Kernel 1: fully independent waves. Each wave owns 16 tokens of one batch
// row (4 DPP-rows x 4 tokens), gathers their embeddings, computes local
// softmax partials, and writes one 132-float record to workspace.
// 8192 waves total = 32 waves/CU -> 100% occupancy cap (vs 50% before).
// No LDS, no __syncthreads: nothing serializes the gather misses.
// ---------------------------------------------------------------------------
__global__ __launch_bounds__(256)
void gather_partial_kernel(const int* __restrict__ x,
                           const float* __restrict__ emb,
                           const float* __restrict__ Wq,
                           const float* __restrict__ bq,
                           float* __restrict__ ws)
{
    const int tid   = threadIdx.x;
    const int wave  = tid >> 6;
    const int lane  = tid & 63;
    const int row   = lane >> 4;   // 4 token-groups (DPP rows) per wave
    const int slot  = lane & 15;   // 16 lanes per token
    const int d0    = slot * 4;    // contiguous 256B half-rows per instr

    // global wave id -> (batch row, chunk of 16 tokens)
    const int gw    = blockIdx.x * 4 + wave;       // 2048 blocks * 4 waves
    const int b     = gw >> 5;                     // 32 chunks per b
    const int chunk = gw & 31;

    const float4 wq0 = *reinterpret_cast<const float4*>(Wq + d0);
    const float4 wq1 = *reinterpret_cast<const float4*>(Wq + 64 + d0);
    const float  bq0 = bq[0];

    // This DPP-row owns 4 consecutive tokens (same across its 16 lanes).
    const int tbase = b * SS + chunk * 16 + row * 4;
    const int4 ia = *reinterpret_cast<const int4*>(x + tbase);
    const int idx[4] = {ia.x, ia.y, ia.z, ia.w};

    // Issue all 8 gather loads up front (independent, all outstanding).
    float4 e0[4], e1[4];
    #pragma unroll
    for (int i = 0; i < 4; ++i) {
        const float* rp = emb + (size_t)idx[i] * EDIM;
        e0[i] = *reinterpret_cast<const float4*>(rp + d0);
        e1[i] = *reinterpret_cast<const float4*>(rp + 64 + d0);
    }

    // Logits for the 4 tokens (independent DPP chains).
    float lp[4];
    #pragma unroll
    for (int i = 0; i < 4; ++i) {
        float q = e0[i].x * wq0.x + e0[i].y * wq0.y + e0[i].z * wq0.z + e0[i].w * wq0.w
                + e1[i].x * wq1.x + e1[i].y * wq1.y + e1[i].z * wq1.z + e1[i].w * wq1.w;
        float s = e0[i].x + e0[i].y + e0[i].z + e0[i].w
                + e1[i].x + e1[i].y + e1[i].z + e1[i].w;
        q = rowsum16(q);
        s = rowsum16(s);
        lp[i] = (q + bq0) * s;
    }

    // Batch-max softmax over the 4 resident tokens.
    float m = fmaxf(fmaxf(lp[0], lp[1]), fmaxf(lp[2], lp[3]));
    float Z = 0.f;
    float acc[8] = {0.f, 0.f, 0.f, 0.f, 0.f, 0.f, 0.f, 0.f};
    #pragma unroll
    for (int i = 0; i < 4; ++i) {
        const float w = __expf(lp[i] - m);   // uniform within the 16-lane row
        Z += w;
        acc[0] = fmaf(w, e0[i].x, acc[0]);  acc[1] = fmaf(w, e0[i].y, acc[1]);
        acc[2] = fmaf(w, e0[i].z, acc[2]);  acc[3] = fmaf(w, e0[i].w, acc[3]);
        acc[4] = fmaf(w, e1[i].x, acc[4]);  acc[5] = fmaf(w, e1[i].y, acc[5]);
        acc[6] = fmaf(w, e1[i].z, acc[6]);  acc[7] = fmaf(w, e1[i].w, acc[7]);
    }

    // Merge the wave's 4 row-groups (cross-row shuffles, once).
    float m1 = fmaxf(m, __shfl_xor(m, 16));
    const float M  = fmaxf(m1, __shfl_xor(m1, 32));
    const float sc = __expf(m - M);
    float Zs = Z * sc;
    Zs += __shfl_xor(Zs, 16);
    Zs += __shfl_xor(Zs, 32);
    #pragma unroll
    for (int j = 0; j < 8; ++j) {
        float a = acc[j] * sc;
        a += __shfl_xor(a, 16);
        a += __shfl_xor(a, 32);
        acc[j] = a;
    }

    // Row 0 writes the wave's partial record straight to workspace.
    float* rec = ws + (size_t)gw * REC;
    if (row == 0) {
        *reinterpret_cast<float4*>(rec + d0)      = make_float4(acc[0], acc[1], acc[2], acc[3]);
        *reinterpret_cast<float4*>(rec + 64 + d0) = make_float4(acc[4], acc[5], acc[6], acc[7]);
        if (slot == 0) { rec[128] = M; rec[129] = Zs; }
    }
}

// ---------------------------------------------------------------------------
// Kernel 2: one wave per batch row. Merge the 32 partials (L2-resident,
// ~4.3 MB total) and do the [128]x[128,2] projection + relu.
// ---------------------------------------------------------------------------
__global__ __launch_bounds__(64)
void merge_project_kernel(const float* __restrict__ ws,
                          const float* __restrict__ Wm,
                          const float* __restrict__ bm,
                          float* __restrict__ out)
{
    const int b    = blockIdx.x;
    const int lane = threadIdx.x;
    const float* base = ws + (size_t)b * CHUNKS_PER_B * REC;

    // lanes 0..31 each own one partial's (M, Z)
    float Ml = -INFINITY, Zl = 0.f;
    if (lane < CHUNKS_PER_B) {
        Ml = base[lane * REC + 128];
        Zl = base[lane * REC + 129];
    }
    float Mb = Ml;
    #pragma unroll
    for (int off = 32; off >= 1; off >>= 1) Mb = fmaxf(Mb, __shfl_xor(Mb, off));

    const float s2 = (lane < CHUNKS_PER_B) ? __expf(Ml - Mb) : 0.f;
    float zt = Zl * s2;
    #pragma unroll
    for (int off = 32; off >= 1; off >>= 1) zt += __shfl_xor(zt, off);

    // Each lane accumulates output dims [2*lane, 2*lane+2) over 32 partials.
    float tv0 = 0.f, tv1 = 0.f;
    #pragma unroll
    for (int p = 0; p < CHUNKS_PER_B; ++p) {
        const float sp = __shfl(s2, p);
        const float2 a2 = *reinterpret_cast<const float2*>(base + p * REC + 2 * lane);
        tv0 = fmaf(a2.x, sp, tv0);
        tv1 = fmaf(a2.y, sp, tv1);
    }
    const float t0 = tv0 / zt, t1 = tv1 / zt;   // t_hat dims 2*lane, 2*lane+1

    const float4 wm = *reinterpret_cast<const float4*>(Wm + 4 * lane);
    float c0 = t0 * wm.x + t1 * wm.z;
    float c1 = t0 * wm.y + t1 * wm.w;
    #pragma unroll
    for (int off = 32; off >= 1; off >>= 1) {
        c0 += __shfl_xor(c0, off);
        c1 += __shfl_xor(c1, off);
    }
    if (lane == 0) {
        out[b * 2 + 0] = fmaxf(c0 + bm[0], 0.f);
        out[b * 2 + 1] = fmaxf(c1 + bm[1], 0.f);
    }
}

extern "C" void kernel_launch(void* const* d_in, const int* in_sizes, int n_in,
                              void* d_out, int out_size, void* d_ws, size_t ws_size,
                              hipStream_t stream) {
    const int*   x   = (const int*)  d_in[0];
    const float* emb = (const float*)d_in[1];
    const float* Wq  = (const float*)d_in[2];
    const float* bq  = (const float*)d_in[3];
    const float* Wm  = (const float*)d_in[4];
    const float* bm  = (const float*)d_in[5];
    float* out = (float*)d_out;
    float* ws  = (float*)d_ws;

    // 2048 blocks x 256 threads = 8192 independent waves (32 waves/CU).
    hipLaunchKernelGGL(gather_partial_kernel, dim3(2048), dim3(256), 0,
                       stream, x, emb, Wq, bq, ws);
    hipLaunchKernelGGL(merge_project_kernel, dim3(BB), dim3(64), 0,
                       stream, ws, Wm, bm, out);
}

// Round 3
// 96.562 us; speedup vs baseline: 1.3446x; 1.0261x over previous
//
#include <hip/hip_runtime.h>
#include <math.h>

#define EDIM 128
#define BB   256
#define SS   512
#define NWAVE 16
#define BLOCK (NWAVE * 64)

// DPP-based add: runs on VALU, keeps the DS pipe free.
template<int CTRL>
__device__ __forceinline__ float dpp_add(float v) {
    int r = __builtin_amdgcn_update_dpp(0, __float_as_int(v), CTRL, 0xF, 0xF, true);
    return v + __int_as_float(r);
}

// Sum across the 16 lanes of a DPP row (all 16 lanes get the total).
__device__ __forceinline__ float rowsum16(float v) {
    v = dpp_add<0xB1>(v);    // quad_perm [1,0,3,2]  (xor 1)
    v = dpp_add<0x4E>(v);    // quad_perm [2,3,0,1]  (xor 2)
    v = dpp_add<0x124>(v);   // row_ror:4
    v = dpp_add<0x128>(v);   // row_ror:8
    return v;
}

__global__ __launch_bounds__(BLOCK)
void fused_embed_attn_kernel(const int* __restrict__ x,
                             const float* __restrict__ emb,
                             const float* __restrict__ Wq,
                             const float* __restrict__ bq,
                             const float* __restrict__ Wm,
                             const float* __restrict__ bm,
                             float* __restrict__ out)
{
    const int b    = blockIdx.x;
    const int tid  = threadIdx.x;
    const int wave = tid >> 6;
    const int lane = tid & 63;
    const int row  = lane >> 4;   // 4 token-groups (DPP rows) per wave
    const int slot = lane & 15;   // 16 lanes per token
    const int d0   = slot * 8;    // 8 dims per lane (strided pair layout:
                                  // e0 at +0, e1 at +16B — both instructions
                                  // land in the same 8 lines; the schedule the
                                  // compiler pipelines best at 64 VGPRs)

    const float4 wq0 = *reinterpret_cast<const float4*>(Wq + d0);
    const float4 wq1 = *reinterpret_cast<const float4*>(Wq + d0 + 4);
    const float  bq0 = bq[0];

    // This lane's group owns 8 consecutive tokens.
    const int tbase = b * SS + wave * 32 + row * 8;
    const int4 ia = *reinterpret_cast<const int4*>(x + tbase);
    const int4 ib = *reinterpret_cast<const int4*>(x + tbase + 4);
    const int idx[8] = {ia.x, ia.y, ia.z, ia.w, ib.x, ib.y, ib.z, ib.w};

    // ---- issue ALL gather loads up front: 16 outstanding float4s/lane ----
    float4 e0[8], e1[8];
    #pragma unroll
    for (int i = 0; i < 8; ++i) {
        const float* rp = emb + (size_t)idx[i] * EDIM + d0;
        e0[i] = *reinterpret_cast<const float4*>(rp);
        e1[i] = *reinterpret_cast<const float4*>(rp + 4);
    }

    // Online-softmax state, per 16-lane row (uniform within row).
    // Online (single-consume) form keeps each e0[i]/e1[i]'s live range short
    // so the whole loop fits in 64 VGPRs without re-loading (the round-1
    // two-pass variant forced reload/serialization: 47.5 us vs ~12 us).
    float m = -INFINITY, Z = 0.f;
    float acc[8] = {0.f, 0.f, 0.f, 0.f, 0.f, 0.f, 0.f, 0.f};

    #pragma unroll
    for (int i = 0; i < 8; ++i) {
        float q = e0[i].x * wq0.x + e0[i].y * wq0.y + e0[i].z * wq0.z + e0[i].w * wq0.w
                + e1[i].x * wq1.x + e1[i].y * wq1.y + e1[i].z * wq1.z + e1[i].w * wq1.w;
        float s = e0[i].x + e0[i].y + e0[i].z + e0[i].w
                + e1[i].x + e1[i].y + e1[i].z + e1[i].w;
        q = rowsum16(q);                   // VALU DPP, no DS traffic
        s = rowsum16(s);
        const float lp = (q + bq0) * s;

        const float mn = fmaxf(m, lp);
        const float al = __expf(m - mn);   // m=-inf first iter -> 0
        const float w  = __expf(lp - mn);
        Z = Z * al + w;
        acc[0] = acc[0] * al + w * e0[i].x;  acc[1] = acc[1] * al + w * e0[i].y;
        acc[2] = acc[2] * al + w * e0[i].z;  acc[3] = acc[3] * al + w * e0[i].w;
        acc[4] = acc[4] * al + w * e1[i].x;  acc[5] = acc[5] * al + w * e1[i].y;
        acc[6] = acc[6] * al + w * e1[i].z;  acc[7] = acc[7] * al + w * e1[i].w;
        m = mn;
    }

    // ---- merge the wave's 4 row-groups (cross-row -> shuffles, once) ----
    float m1 = fmaxf(m, __shfl_xor(m, 16));
    const float M  = fmaxf(m1, __shfl_xor(m1, 32));
    const float sc = __expf(m - M);
    float Zs = Z * sc;
    Zs += __shfl_xor(Zs, 16);
    Zs += __shfl_xor(Zs, 32);
    #pragma unroll
    for (int j = 0; j < 8; ++j) {
        float a = acc[j] * sc;
        a += __shfl_xor(a, 16);
        a += __shfl_xor(a, 32);
        acc[j] = a;
    }

    // ---- block-level merge of the 16 wave partials ----
    __shared__ float sm[NWAVE];
    __shared__ float szv[NWAVE];
    __shared__ float sacc[NWAVE][EDIM];

    if (row == 0) {
        *reinterpret_cast<float4*>(&sacc[wave][d0])     = make_float4(acc[0], acc[1], acc[2], acc[3]);
        *reinterpret_cast<float4*>(&sacc[wave][d0 + 4]) = make_float4(acc[4], acc[5], acc[6], acc[7]);
        if (slot == 0) { sm[wave] = M; szv[wave] = Zs; }
    }
    __syncthreads();

    // wave 0: combine partials, project [128]x[128,2], relu, store
    if (tid < 64) {
        float Mb = sm[0];
        #pragma unroll
        for (int w = 1; w < NWAVE; ++w) Mb = fmaxf(Mb, sm[w]);
        float zt = 0.f, tv0 = 0.f, tv1 = 0.f;
        #pragma unroll
        for (int w = 0; w < NWAVE; ++w) {
            const float s2 = __expf(sm[w] - Mb);
            zt += szv[w] * s2;
            const float2 a2 = *reinterpret_cast<const float2*>(&sacc[w][2 * tid]);
            tv0 += a2.x * s2;
            tv1 += a2.y * s2;
        }
        const float t0 = tv0 / zt, t1 = tv1 / zt;   // t_hat dims 2*tid, 2*tid+1
        const float4 wm = *reinterpret_cast<const float4*>(Wm + 4 * tid);
        float c0 = t0 * wm.x + t1 * wm.z;
        float c1 = t0 * wm.y + t1 * wm.w;
        #pragma unroll
        for (int off = 32; off >= 1; off >>= 1) {
            c0 += __shfl_xor(c0, off);
            c1 += __shfl_xor(c1, off);
        }
        if (tid == 0) {
            out[b * 2 + 0] = fmaxf(c0 + bm[0], 0.f);
            out[b * 2 + 1] = fmaxf(c1 + bm[1], 0.f);
        }
    }
}

extern "C" void kernel_launch(void* const* d_in, const int* in_sizes, int n_in,
                              void* d_out, int out_size, void* d_ws, size_t ws_size,
                              hipStream_t stream) {
    const int*   x   = (const int*)  d_in[0];
    const float* emb = (const float*)d_in[1];
    const float* Wq  = (const float*)d_in[2];
    const float* bq  = (const float*)d_in[3];
    const float* Wm  = (const float*)d_in[4];
    const float* bm  = (const float*)d_in[5];
    float* out = (float*)d_out;

    hipLaunchKernelGGL(fused_embed_attn_kernel, dim3(BB), dim3(BLOCK), 0,
                       stream, x, emb, Wq, bq, Wm, bm, out);
}